// Round 8
// baseline (189.986 us; speedup 1.0000x reference)
//
#include <hip/hip_runtime.h>
#include <hip/hip_bf16.h>

// Pipeline:
//  k_wconv : qkv_w/proj_w fp32 -> bf16 (q rows pre-scaled by temperature[h]/8 * LOG2E)
//  k_pool  : x (512,256,256) -> pooled xp (512,64,64) fp32 + per-group partial stats
//  k_stats : reduce partials -> mean/rstd per group
//  k_xr    : xr = GN_affine(xp) + posenc -> bf16 (512,4096)
//  k_gemm  : qkv = Wq(1536,512) x xr(512,4096) -> bf16
//  k_perm  : Q/K/V -> fragment-ordered tiles (Q: 32-n tiles; K/V: 64-m tiles)
//  k_attn  : flash attn, m==0 softmax (S bounded << 88), lane-local l,
//            64-key tiles, TRIPLE-buffered LDS, ONE barrier/tile, counted vmcnt
//  k_merge : combine 8 seg partials (sum num / sum den) -> attn_b bf16
//  k_gemm  : low = Wp(512,512) x attn(512,4096) -> bf16
//  k_up    : out = x + gamma * (bilerp_4x(low) + proj_b)

typedef __attribute__((ext_vector_type(4))) short short4v;
typedef __attribute__((ext_vector_type(8))) short short8v;
typedef __attribute__((ext_vector_type(4))) float f32x4;
typedef __attribute__((ext_vector_type(4))) unsigned int u32x4;

#define MFMA16(a, b, c) __builtin_amdgcn_mfma_f32_16x16x32_bf16(a, b, c, 0, 0, 0)

__device__ __forceinline__ unsigned short bf16r(float f) {
    unsigned int u = __builtin_bit_cast(unsigned int, f);
    u += 0x7fffu + ((u >> 16) & 1u);
    return (unsigned short)(u >> 16);
}
__device__ __forceinline__ float bff(unsigned short s) {
    unsigned int u = ((unsigned int)s) << 16;
    return __builtin_bit_cast(float, u);
}
__device__ __forceinline__ unsigned int fbits(float f) {
    return __builtin_bit_cast(unsigned int, f);
}

typedef const __attribute__((address_space(1))) unsigned int guint;
typedef __attribute__((address_space(3))) unsigned int luint;
__device__ __forceinline__ void gload16(const void* g, void* l) {
    __builtin_amdgcn_global_load_lds((guint*)g, (luint*)l, 16, 0, 0);
}

// ---------------- weight conversion (q rows: temp/8 * log2(e) folded in) ----------------
__global__ __launch_bounds__(256) void k_wconv(const float* __restrict__ qkv_w,
                                               const float* __restrict__ proj_w,
                                               const float* __restrict__ temp,
                                               unsigned short* __restrict__ wq_b,
                                               unsigned short* __restrict__ wp_b) {
    int idx = blockIdx.x * 256 + threadIdx.x;
    const int NQ = 1536 * 512;
    if (idx < NQ) {
        int o = idx >> 9;
        float sc = (o < 512) ? temp[o >> 6] * 0.125f * 1.44269504f : 1.0f;
        wq_b[idx] = bf16r(qkv_w[idx] * sc);
    } else {
        int j = idx - NQ;
        wp_b[j] = bf16r(proj_w[j]);
    }
}

// ---------------- pool + group partial stats ----------------
__global__ __launch_bounds__(256) void k_pool(const float* __restrict__ x,
                                              float* __restrict__ xp,
                                              float* __restrict__ partials) {
    int hr = blockIdx.x;
    int c  = blockIdx.y;
    int t = threadIdx.x;
    int r = t >> 6, wq = t & 63;
    const float4* src = (const float4*)(x + (size_t)c * 65536 + (size_t)(4 * hr + r) * 256 + 4 * wq);
    float4 v = *src;
    float s4 = v.x + v.y + v.z + v.w;
    float q4 = v.x * v.x + v.y * v.y + v.z * v.z + v.w * v.w;

    __shared__ float sm[256];
    __shared__ float wq4[4];
    sm[t] = s4;
    float qq = q4;
#pragma unroll
    for (int off = 1; off < 64; off <<= 1) qq += __shfl_xor(qq, off, 64);
    if ((t & 63) == 0) wq4[t >> 6] = qq;
    __syncthreads();
    if (t < 64) {
        float cs = sm[t] + sm[64 + t] + sm[128 + t] + sm[192 + t];
        xp[(size_t)c * 4096 + hr * 64 + t] = cs * (1.0f / 16.0f);
        float ts = cs;
#pragma unroll
        for (int off = 1; off < 64; off <<= 1) ts += __shfl_xor(ts, off, 64);
        if (t == 0) {
            int g = c >> 6;
            int slot = (c & 63) * 64 + hr;
            partials[(size_t)(g * 4096 + slot) * 2 + 0] = ts;
            partials[(size_t)(g * 4096 + slot) * 2 + 1] = wq4[0] + wq4[1] + wq4[2] + wq4[3];
        }
    }
}

// ---------------- group stats finalize ----------------
__global__ __launch_bounds__(256) void k_stats(const float* __restrict__ partials,
                                               float* __restrict__ gstats) {
    int g = blockIdx.x;
    int t = threadIdx.x;
    float s = 0.f, q = 0.f;
    for (int i = t; i < 4096; i += 256) {
        s += partials[(size_t)(g * 4096 + i) * 2 + 0];
        q += partials[(size_t)(g * 4096 + i) * 2 + 1];
    }
#pragma unroll
    for (int off = 1; off < 64; off <<= 1) {
        s += __shfl_xor(s, off, 64);
        q += __shfl_xor(q, off, 64);
    }
    __shared__ float ss[4], qs[4];
    if ((t & 63) == 0) { ss[t >> 6] = s; qs[t >> 6] = q; }
    __syncthreads();
    if (t == 0) {
        float S = ss[0] + ss[1] + ss[2] + ss[3];
        float Q = qs[0] + qs[1] + qs[2] + qs[3];
        const float inv = 1.0f / 4194304.0f;
        float m = S * inv;
        float var = Q * inv - m * m;
        gstats[2 * g] = m;
        gstats[2 * g + 1] = rsqrtf(var + 1e-5f);
    }
}

// ---------------- GN affine + positional encoding -> bf16 ----------------
__global__ __launch_bounds__(256) void k_xr(const float* __restrict__ xp,
                                            const float* __restrict__ gs,
                                            const float* __restrict__ gw,
                                            const float* __restrict__ gb,
                                            unsigned short* __restrict__ xr) {
    int idx = blockIdx.x * 256 + threadIdx.x;
    int c = idx >> 12, n = idx & 4095;
    int hr = n >> 6, wr = n & 63;
    int g = c >> 6;
    float m = gs[2 * g], rs = gs[2 * g + 1];
    float xn = (xp[idx] - m) * rs * gw[c] + gb[c];
    int i = c >> 2, kind = c & 3;
    float di = expf(-(float)i * 0.07195578415606394f);
    float arg = ((kind < 2) ? (float)hr : (float)wr) * di;
    float pe = 0.01f * ((kind & 1) ? cosf(arg) : sinf(arg));
    xr[idx] = bf16r(xn + pe);
}

// ---------------- bf16 GEMM: C[M,4096] = A[M,512] * B[512,4096] ----------------
__global__ __launch_bounds__(256) void k_gemm(const unsigned short* __restrict__ A,
                                              const unsigned short* __restrict__ B,
                                              unsigned short* __restrict__ C) {
    __shared__ unsigned short As[128][36];
    __shared__ unsigned short Bs[128][36];
    int t = threadIdx.x;
    int w = t >> 6, l = t & 63, l15 = l & 15, lg = l >> 4;
    int wrow = w >> 1, wcol = w & 1;
    int m0 = blockIdx.y * 128, n0 = blockIdx.x * 128;
    f32x4 acc[4][4] = {};

    for (int k0 = 0; k0 < 512; k0 += 32) {
#pragma unroll
        for (int i = 0; i < 4; i++) {
            int idx = t + 256 * i;
            int row = idx >> 3, kc = idx & 7;
            short4v av = *(const short4v*)(A + (size_t)(m0 + row) * 512 + k0 + 4 * kc);
            *(short4v*)&As[row][4 * kc] = av;
        }
#pragma unroll
        for (int i = 0; i < 4; i++) {
            int idx = t + 256 * i;
            int kr = idx >> 5, nc = idx & 31;
            short4v bv = *(const short4v*)(B + (size_t)(k0 + kr) * 4096 + n0 + 4 * nc);
#pragma unroll
            for (int j = 0; j < 4; j++) Bs[4 * nc + j][kr] = (unsigned short)bv[j];
        }
        __syncthreads();

        short8v af[4];
#pragma unroll
        for (int mi = 0; mi < 4; mi++) {
            int ar = wrow * 64 + mi * 16 + l15;
            short4v a0 = *(const short4v*)&As[ar][4 * lg];
            short4v a1 = *(const short4v*)&As[ar][16 + 4 * lg];
            af[mi] = __builtin_shufflevector(a0, a1, 0, 1, 2, 3, 4, 5, 6, 7);
        }
#pragma unroll
        for (int ni = 0; ni < 4; ni++) {
            int bc = wcol * 64 + ni * 16 + l15;
            short4v b0 = *(const short4v*)&Bs[bc][4 * lg];
            short4v b1 = *(const short4v*)&Bs[bc][16 + 4 * lg];
            short8v bf = __builtin_shufflevector(b0, b1, 0, 1, 2, 3, 4, 5, 6, 7);
#pragma unroll
            for (int mi = 0; mi < 4; mi++) acc[mi][ni] = MFMA16(af[mi], bf, acc[mi][ni]);
        }
        __syncthreads();
    }
#pragma unroll
    for (int mi = 0; mi < 4; mi++)
#pragma unroll
        for (int ni = 0; ni < 4; ni++) {
            int row = m0 + wrow * 64 + mi * 16 + 4 * lg;
            int col = n0 + wcol * 64 + ni * 16 + l15;
#pragma unroll
            for (int r = 0; r < 4; r++)
                C[(size_t)(row + r) * 4096 + col] = bf16r(acc[mi][ni][r]);
        }
}

// ---------------- fragment-order permute prepass ----------------
// Q (z=0): 32-n tiles, qtg[(h*128+nu)*2048 + ((s*4+lg)*32+col)*8 + j]
// K (z=1): 64-m tiles, ktg[(h*64+T)*4096 + ((s*4+lg)*64+m)*8 + j]
// V (z=2): 64-m tiles, vtg[(h*64+T)*4096 + ((mh*4+lg)*64+d)*8 + j]
//          chunk holds {V[d][mh*32+4lg+j] j<4, V[d][mh*32+16+4lg+j]}
__global__ __launch_bounds__(256) void k_perm(const unsigned short* __restrict__ qkv,
                                              unsigned short* __restrict__ qtg,
                                              unsigned short* __restrict__ ktg,
                                              unsigned short* __restrict__ vtg) {
    __shared__ unsigned short lt[64][72];
    int t = threadIdx.x;
    int tile = blockIdx.x, h = blockIdx.y, z = blockIdx.z;
    int base = (z == 0 ? 0 : (z == 1 ? 512 : 1024)) + h * 64;
#pragma unroll
    for (int i = 0; i < 2; i++) {
        int idx = t + 256 * i;
        int row = idx >> 3, sg = idx & 7;
        *(short8v*)&lt[row][sg * 8] =
            *(const short8v*)(qkv + (size_t)(base + row) * 4096 + tile * 64 + sg * 8);
    }
    __syncthreads();
#pragma unroll
    for (int i = 0; i < 2; i++) {
        int c = t + 256 * i;
        unsigned short o[8];
        unsigned short* dst;
        if (z == 0) {
            int nh = c >> 8, cl = c & 255;
            int s = cl >> 7, lgc = (cl >> 5) & 3, col = cl & 31;
#pragma unroll
            for (int j = 0; j < 4; j++) {
                o[j] = lt[s * 32 + 4 * lgc + j][nh * 32 + col];
                o[4 + j] = lt[s * 32 + 16 + 4 * lgc + j][nh * 32 + col];
            }
            dst = qtg + ((size_t)(h * 128 + tile * 2 + nh)) * 2048 + cl * 8;
        } else if (z == 1) {
            int s = c >> 8, lgc = (c >> 6) & 3, m = c & 63;
#pragma unroll
            for (int j = 0; j < 4; j++) {
                o[j] = lt[s * 32 + 4 * lgc + j][m];
                o[4 + j] = lt[s * 32 + 16 + 4 * lgc + j][m];
            }
            dst = ktg + ((size_t)(h * 64 + tile)) * 4096 + c * 8;
        } else {
            int mh = c >> 8, lgc = (c >> 6) & 3, d = c & 63;
#pragma unroll
            for (int j = 0; j < 4; j++) {
                o[j] = lt[d][mh * 32 + 4 * lgc + j];
                o[4 + j] = lt[d][mh * 32 + 16 + 4 * lgc + j];
            }
            dst = vtg + ((size_t)(h * 64 + tile)) * 4096 + c * 8;
        }
        *(short8v*)dst = *(const short8v*)o;
    }
}

// ---------------- flash attention: 64-key tiles, triple-buffer, 1 barrier/tile ----------------
// grid (16 qt, 8 h, 8 seg), 512 threads. Wave w -> 32 n; segment = 512 keys = 8 tiles of 64.
// m==0 softmax (S' = S*log2e via Wq fold; exp2 direct), lane-local l.
// Pipeline per tile j: vmcnt(2) [own stage(j) done] -> s_barrier [all stages(j) done AND
// all compute(j-1) done] -> STAGE(j+2) into buf freed by compute(j-1) -> compute(j).
__global__ __launch_bounds__(512, 4) void k_attn(const unsigned short* __restrict__ qtg,
                                                 const unsigned short* __restrict__ ktg,
                                                 const unsigned short* __restrict__ vtg,
                                                 unsigned short* __restrict__ opart,
                                                 float* __restrict__ lgl) {
    __shared__ __align__(16) unsigned short kbuf[3][4096];
    __shared__ __align__(16) unsigned short vbuf[3][4096];
    int t = threadIdx.x;
    int l = t & 63, l15 = l & 15, lg = l >> 4, w = t >> 6;
    int qt = blockIdx.x, h = blockIdx.y, seg = blockIdx.z;
    int nu = qt * 8 + w;

    const unsigned short* qb = qtg + ((size_t)(h * 128 + nu)) * 2048;
    const unsigned short* kb = ktg + ((size_t)(h * 64 + seg * 8)) * 4096;
    const unsigned short* vb = vtg + ((size_t)(h * 64 + seg * 8)) * 4096;

    // Q fragments (B-operand), loaded once
    short8v qf[2][2];
#pragma unroll
    for (int ng = 0; ng < 2; ng++)
#pragma unroll
        for (int s = 0; s < 2; s++)
            qf[ng][s] = *(const short8v*)(qb + ((s * 4 + lg) * 32 + ng * 16 + l15) * 8);

    // staging: threads 0-255 K, 256-511 V; 2 gload16 each per 64-key tile (8KB each)
    int st = t & 255;
    const unsigned short* sp = ((t >= 256) ? vb : kb) + st * 8;
    unsigned short* ld0 = ((t >= 256) ? &vbuf[0][0] : &kbuf[0][0]) + st * 8;

    f32x4 od[2][4] = {};
    float lsum[2] = {0.f, 0.f};

#define STAGE(kt, b)                                      \
    {                                                     \
        gload16(sp + (kt) * 4096, ld0 + (b) * 4096);      \
        gload16(sp + (kt) * 4096 + 2048, ld0 + (b) * 4096 + 2048); \
    }

    STAGE(0, 0);
    STAGE(1, 1);

    int cur = 0, nxt = 2;
#pragma unroll 1
    for (int j = 0; j < 8; j++) {
        if (j < 7) {
            asm volatile("s_waitcnt vmcnt(2)" ::: "memory");
        } else {
            asm volatile("s_waitcnt vmcnt(0)" ::: "memory");
        }
        __builtin_amdgcn_s_barrier();
        __builtin_amdgcn_sched_barrier(0);  // pin: no LDS reads/stages cross the barrier
        if (j < 6) STAGE(j + 2, nxt);

        const unsigned short* kl = &kbuf[0][0] + cur * 4096;
        const unsigned short* vl = &vbuf[0][0] + cur * 4096;

        // phase 1: S^T = K^T q for 64 keys (4 mf fragments), exp2 inline, pack P
        short8v pb[2][2];
        float p[2][2][4];
#pragma unroll
        for (int mf = 0; mf < 4; mf++) {
            short8v k0 = *(const short8v*)(kl + ((0 + lg) * 64 + mf * 16 + l15) * 8);
            short8v k1 = *(const short8v*)(kl + ((4 + lg) * 64 + mf * 16 + l15) * 8);
            f32x4 s0 = {}, s1 = {};
            __builtin_amdgcn_s_setprio(1);
            s0 = MFMA16(k0, qf[0][0], s0);
            s0 = MFMA16(k1, qf[0][1], s0);
            s1 = MFMA16(k0, qf[1][0], s1);
            s1 = MFMA16(k1, qf[1][1], s1);
            __builtin_amdgcn_s_setprio(0);
            int half = mf & 1;
#pragma unroll
            for (int r = 0; r < 4; r++) {
                p[0][half][r] = __builtin_amdgcn_exp2f(s0[r]);
                p[1][half][r] = __builtin_amdgcn_exp2f(s1[r]);
            }
            lsum[0] += (p[0][half][0] + p[0][half][1]) + (p[0][half][2] + p[0][half][3]);
            lsum[1] += (p[1][half][0] + p[1][half][1]) + (p[1][half][2] + p[1][half][3]);
            if (half) {
                int mh = mf >> 1;
#pragma unroll
                for (int ng = 0; ng < 2; ng++) {
                    u32x4 P;
                    P[0] = __builtin_amdgcn_perm(fbits(p[ng][0][1]), fbits(p[ng][0][0]), 0x07060302u);
                    P[1] = __builtin_amdgcn_perm(fbits(p[ng][0][3]), fbits(p[ng][0][2]), 0x07060302u);
                    P[2] = __builtin_amdgcn_perm(fbits(p[ng][1][1]), fbits(p[ng][1][0]), 0x07060302u);
                    P[3] = __builtin_amdgcn_perm(fbits(p[ng][1][3]), fbits(p[ng][1][2]), 0x07060302u);
                    pb[ng][mh] = __builtin_bit_cast(short8v, P);
                }
            }
        }

        // phase 2: O^T += V P^T (two 32-key halves)
        __builtin_amdgcn_s_setprio(1);
#pragma unroll
        for (int mh = 0; mh < 2; mh++)
#pragma unroll
            for (int dg = 0; dg < 4; dg++) {
                short8v vf = *(const short8v*)(vl + ((mh * 4 + lg) * 64 + dg * 16 + l15) * 8);
                od[0][dg] = MFMA16(vf, pb[0][mh], od[0][dg]);
                od[1][dg] = MFMA16(vf, pb[1][mh], od[1][dg]);
            }
        __builtin_amdgcn_s_setprio(0);

        cur = (cur == 2) ? 0 : cur + 1;
        nxt = (nxt == 2) ? 0 : nxt + 1;
    }
#undef STAGE

    // cross-lane l reduce (once per kernel)
#pragma unroll
    for (int ng = 0; ng < 2; ng++) {
        lsum[ng] += __shfl_xor(lsum[ng], 16, 64);
        lsum[ng] += __shfl_xor(lsum[ng], 32, 64);
    }

    unsigned short* op = opart + ((size_t)(seg * 512 + h * 64)) * 4096 + nu * 32;
#pragma unroll
    for (int ng = 0; ng < 2; ng++)
#pragma unroll
        for (int dg = 0; dg < 4; dg++)
#pragma unroll
            for (int r = 0; r < 4; r++) {
                int d = dg * 16 + 4 * lg + r;
                op[(size_t)d * 4096 + ng * 16 + l15] = bf16r(od[ng][dg][r]);
            }
    if (lg == 0) {
#pragma unroll
        for (int ng = 0; ng < 2; ng++)
            lgl[(size_t)(seg * 8 + h) * 4096 + nu * 32 + ng * 16 + l15] = lsum[ng];
    }
}

// ---------------- merge 8 seg partials (m==0: plain sums) -> attn bf16 ----------------
__global__ __launch_bounds__(256) void k_merge(const unsigned short* __restrict__ opart,
                                               const float* __restrict__ lgl,
                                               unsigned short* __restrict__ attn_b) {
    int bid = blockIdx.x, t = threadIdx.x;
    int row = bid >> 2;               // h*64 + d
    int n0 = (bid & 3) * 1024 + t * 4;
    int h = row >> 6;

    f32x4 den = {};
    float num[4] = {};
#pragma unroll
    for (int s = 0; s < 8; s++) {
        f32x4 lv = *(const f32x4*)(lgl + (size_t)(s * 8 + h) * 4096 + n0);
        den += lv;
        short4v ov = *(const short4v*)(opart + (size_t)s * 2097152 + (size_t)row * 4096 + n0);
#pragma unroll
        for (int j = 0; j < 4; j++) num[j] += bff((unsigned short)ov[j]);
    }
    unsigned short res[4];
#pragma unroll
    for (int j = 0; j < 4; j++) res[j] = bf16r(num[j] / den[j]);
    *(short4v*)(attn_b + (size_t)row * 4096 + n0) = *(const short4v*)res;
}

// ---------------- bilinear upsample 64->256 + bias + residual (float4) ----------------
__global__ __launch_bounds__(256) void k_up(const float* __restrict__ x,
                                            const unsigned short* __restrict__ low,
                                            const float* __restrict__ proj_b,
                                            const float* __restrict__ gamma,
                                            float* __restrict__ out) {
    int t = threadIdx.x;
    int hs = t >> 6;
    int hh = blockIdx.x * 4 + hs;
    int c = blockIdx.y;
    int a = t & 63;

    int ph = hh & 3, Ah = hh >> 2;
    int y0 = Ah + ((ph < 2) ? -1 : 0);
    float fy = (ph < 2) ? (0.625f + 0.25f * ph) : (0.125f + 0.25f * (ph - 2));
    int y1 = min(y0 + 1, 63); y0 = max(y0, 0);

    const unsigned short* L0 = low + (size_t)c * 4096 + y0 * 64;
    const unsigned short* L1 = low + (size_t)c * 4096 + y1 * 64;
    int am = max(a - 1, 0), ap = min(a + 1, 63);
    float gy = 1.f - fy;
    float vm = gy * bff(L0[am]) + fy * bff(L1[am]);
    float v0 = gy * bff(L0[a])  + fy * bff(L1[a]);
    float vp = gy * bff(L0[ap]) + fy * bff(L1[ap]);

    float pb = proj_b[c], g = gamma[0];
    size_t idx = (size_t)c * 65536 + (size_t)hh * 256 + a * 4;
    float4 xi = *(const float4*)(x + idx);
    float4 o;
    o.x = xi.x + g * (0.375f * vm + 0.625f * v0 + pb);
    o.y = xi.y + g * (0.125f * vm + 0.875f * v0 + pb);
    o.z = xi.z + g * (0.875f * v0 + 0.125f * vp + pb);
    o.w = xi.w + g * (0.625f * v0 + 0.375f * vp + pb);
    *(float4*)(out + idx) = o;
}

extern "C" void kernel_launch(void* const* d_in, const int* in_sizes, int n_in,
                              void* d_out, int out_size, void* d_ws, size_t ws_size,
                              hipStream_t stream) {
    const float* x     = (const float*)d_in[0];
    const float* gnw   = (const float*)d_in[1];
    const float* gnb   = (const float*)d_in[2];
    const float* qkvw  = (const float*)d_in[3];
    const float* projw = (const float*)d_in[4];
    const float* projb = (const float*)d_in[5];
    const float* gamma = (const float*)d_in[6];
    const float* temp  = (const float*)d_in[7];

    char* ws = (char*)d_ws;
    const size_t MB = 1u << 20;
    float* gstats          = (float*)(ws + 0);
    float* partials        = (float*)(ws + 1024);
    float* xp              = (float*)(ws + 1 * MB);            // dead after k_xr
    unsigned short* qtg    = (unsigned short*)(ws + 1 * MB);   // reuses xp (4MB)
    unsigned short* ktg    = (unsigned short*)(ws + 5 * MB);   // 4MB
    unsigned short* xr_b   = (unsigned short*)(ws + 9 * MB);   // dead after gemm1
    unsigned short* vtg    = (unsigned short*)(ws + 9 * MB);   // reuses xr_b (4MB)
    unsigned short* wq_b   = (unsigned short*)(ws + 13 * MB);
    unsigned short* wp_b   = (unsigned short*)(ws + 15 * MB);
    unsigned short* qkv_b  = (unsigned short*)(ws + 16 * MB);
    unsigned short* attn_b = (unsigned short*)(ws + 28 * MB);
    unsigned short* low_b  = (unsigned short*)(ws + 32 * MB);
    float* out = (float*)d_out;
    unsigned short* opart = (unsigned short*)d_out;              // 32MB scratch in d_out
    float* lgl = (float*)((char*)d_out + 32 * MB);               // 1MB scratch in d_out

    k_wconv<<<4096, 256, 0, stream>>>(qkvw, projw, temp, wq_b, wp_b);
    k_pool<<<dim3(64, 512), 256, 0, stream>>>(x, xp, partials);
    k_stats<<<8, 256, 0, stream>>>(partials, gstats);
    k_xr<<<8192, 256, 0, stream>>>(xp, gstats, gnw, gnb, xr_b);
    k_gemm<<<dim3(32, 12), 256, 0, stream>>>(wq_b, xr_b, qkv_b);
    k_perm<<<dim3(64, 8, 3), 256, 0, stream>>>(qkv_b, qtg, ktg, vtg);
    k_attn<<<dim3(16, 8, 8), 512, 0, stream>>>(qtg, ktg, vtg, opart, lgl);
    k_merge<<<2048, 256, 0, stream>>>(opart, lgl, attn_b);
    k_gemm<<<dim3(32, 4), 256, 0, stream>>>(wp_b, attn_b, low_b);
    k_up<<<dim3(64, 512), 256, 0, stream>>>(x, low_b, projb, gamma, out);
}

// Round 9
// 185.578 us; speedup vs baseline: 1.0238x; 1.0238x over previous
//
#include <hip/hip_runtime.h>
#include <hip/hip_bf16.h>

// Pipeline (9 launches):
//  k_pool  : x -> pooled xp + group partial stats  [+ fused wconv: weights -> bf16]
//  k_stats : reduce partials -> mean/rstd per group
//  k_xr    : xr = GN_affine(xp) + posenc -> bf16 (512,4096)
//  k_gemm  : qkv = Wq(1536,512) x xr(512,4096) -> bf16
//  k_perm  : Q/K/V -> fragment-ordered tiles (Q: 32-n tiles; K/V: 64-m tiles)
//  k_attn  : flash attn, m==0 softmax, lane-local l, 64-key tiles, dbuf LDS,
//            counted vmcnt, 256-thr/4-wave blocks @ 5 blocks/CU, coalesced partials
//  k_merge : sum 8 seg partials -> attn_bT (n-major) bf16, fully coalesced
//  k_gemmT : low = Wp(512,512) x attn_bT^T -> bf16 (B-staging transpose-free)
//  k_up    : out = x + gamma * (bilerp_4x(low) + proj_b)

typedef __attribute__((ext_vector_type(4))) short short4v;
typedef __attribute__((ext_vector_type(8))) short short8v;
typedef __attribute__((ext_vector_type(4))) float f32x4;
typedef __attribute__((ext_vector_type(4))) unsigned int u32x4;

#define MFMA16(a, b, c) __builtin_amdgcn_mfma_f32_16x16x32_bf16(a, b, c, 0, 0, 0)

__device__ __forceinline__ unsigned short bf16r(float f) {
    unsigned int u = __builtin_bit_cast(unsigned int, f);
    u += 0x7fffu + ((u >> 16) & 1u);
    return (unsigned short)(u >> 16);
}
__device__ __forceinline__ float bff(unsigned short s) {
    unsigned int u = ((unsigned int)s) << 16;
    return __builtin_bit_cast(float, u);
}
__device__ __forceinline__ unsigned int fbits(float f) {
    return __builtin_bit_cast(unsigned int, f);
}

typedef const __attribute__((address_space(1))) unsigned int guint;
typedef __attribute__((address_space(3))) unsigned int luint;
__device__ __forceinline__ void gload16(const void* g, void* l) {
    __builtin_amdgcn_global_load_lds((guint*)g, (luint*)l, 16, 0, 0);
}

// ---------------- pool + group partial stats (+ fused weight conversion) ----------------
__global__ __launch_bounds__(256) void k_pool(const float* __restrict__ x,
                                              float* __restrict__ xp,
                                              float* __restrict__ partials,
                                              const float* __restrict__ qkv_w,
                                              const float* __restrict__ proj_w,
                                              const float* __restrict__ temp,
                                              unsigned short* __restrict__ wq_b,
                                              unsigned short* __restrict__ wp_b) {
    if (blockIdx.x >= 64) {
        // fused wconv: q rows scaled by temp[h]/8 * log2(e)
        int idx = ((blockIdx.x - 64) * 512 + blockIdx.y) * 256 + threadIdx.x;
        const int NQ = 1536 * 512;
        const int NTOT = NQ + 512 * 512;
        if (idx < NQ) {
            int o = idx >> 9;
            float sc = (o < 512) ? temp[o >> 6] * 0.125f * 1.44269504f : 1.0f;
            wq_b[idx] = bf16r(qkv_w[idx] * sc);
        } else if (idx < NTOT) {
            wp_b[idx - NQ] = bf16r(proj_w[idx - NQ]);
        }
        return;
    }
    int hr = blockIdx.x;
    int c  = blockIdx.y;
    int t = threadIdx.x;
    int r = t >> 6, wq = t & 63;
    const float4* src = (const float4*)(x + (size_t)c * 65536 + (size_t)(4 * hr + r) * 256 + 4 * wq);
    float4 v = *src;
    float s4 = v.x + v.y + v.z + v.w;
    float q4 = v.x * v.x + v.y * v.y + v.z * v.z + v.w * v.w;

    __shared__ float sm[256];
    __shared__ float wq4[4];
    sm[t] = s4;
    float qq = q4;
#pragma unroll
    for (int off = 1; off < 64; off <<= 1) qq += __shfl_xor(qq, off, 64);
    if ((t & 63) == 0) wq4[t >> 6] = qq;
    __syncthreads();
    if (t < 64) {
        float cs = sm[t] + sm[64 + t] + sm[128 + t] + sm[192 + t];
        xp[(size_t)c * 4096 + hr * 64 + t] = cs * (1.0f / 16.0f);
        float ts = cs;
#pragma unroll
        for (int off = 1; off < 64; off <<= 1) ts += __shfl_xor(ts, off, 64);
        if (t == 0) {
            int g = c >> 6;
            int slot = (c & 63) * 64 + hr;
            partials[(size_t)(g * 4096 + slot) * 2 + 0] = ts;
            partials[(size_t)(g * 4096 + slot) * 2 + 1] = wq4[0] + wq4[1] + wq4[2] + wq4[3];
        }
    }
}

// ---------------- group stats finalize ----------------
__global__ __launch_bounds__(256) void k_stats(const float* __restrict__ partials,
                                               float* __restrict__ gstats) {
    int g = blockIdx.x;
    int t = threadIdx.x;
    float s = 0.f, q = 0.f;
    for (int i = t; i < 4096; i += 256) {
        s += partials[(size_t)(g * 4096 + i) * 2 + 0];
        q += partials[(size_t)(g * 4096 + i) * 2 + 1];
    }
#pragma unroll
    for (int off = 1; off < 64; off <<= 1) {
        s += __shfl_xor(s, off, 64);
        q += __shfl_xor(q, off, 64);
    }
    __shared__ float ss[4], qs[4];
    if ((t & 63) == 0) { ss[t >> 6] = s; qs[t >> 6] = q; }
    __syncthreads();
    if (t == 0) {
        float S = ss[0] + ss[1] + ss[2] + ss[3];
        float Q = qs[0] + qs[1] + qs[2] + qs[3];
        const float inv = 1.0f / 4194304.0f;
        float m = S * inv;
        float var = Q * inv - m * m;
        gstats[2 * g] = m;
        gstats[2 * g + 1] = rsqrtf(var + 1e-5f);
    }
}

// ---------------- GN affine + positional encoding -> bf16 ----------------
__global__ __launch_bounds__(256) void k_xr(const float* __restrict__ xp,
                                            const float* __restrict__ gs,
                                            const float* __restrict__ gw,
                                            const float* __restrict__ gb,
                                            unsigned short* __restrict__ xr) {
    int idx = blockIdx.x * 256 + threadIdx.x;
    int c = idx >> 12, n = idx & 4095;
    int hr = n >> 6, wr = n & 63;
    int g = c >> 6;
    float m = gs[2 * g], rs = gs[2 * g + 1];
    float xn = (xp[idx] - m) * rs * gw[c] + gb[c];
    int i = c >> 2, kind = c & 3;
    float di = expf(-(float)i * 0.07195578415606394f);
    float arg = ((kind < 2) ? (float)hr : (float)wr) * di;
    float pe = 0.01f * ((kind & 1) ? cosf(arg) : sinf(arg));
    xr[idx] = bf16r(xn + pe);
}

// ---------------- bf16 GEMM: C[M,4096] = A[M,512] * B[512,4096] (B c-major) ----------------
__global__ __launch_bounds__(256) void k_gemm(const unsigned short* __restrict__ A,
                                              const unsigned short* __restrict__ B,
                                              unsigned short* __restrict__ C) {
    __shared__ unsigned short As[128][36];
    __shared__ unsigned short Bs[128][36];
    int t = threadIdx.x;
    int w = t >> 6, l = t & 63, l15 = l & 15, lg = l >> 4;
    int wrow = w >> 1, wcol = w & 1;
    int m0 = blockIdx.y * 128, n0 = blockIdx.x * 128;
    f32x4 acc[4][4] = {};

    for (int k0 = 0; k0 < 512; k0 += 32) {
#pragma unroll
        for (int i = 0; i < 4; i++) {
            int idx = t + 256 * i;
            int row = idx >> 3, kc = idx & 7;
            short4v av = *(const short4v*)(A + (size_t)(m0 + row) * 512 + k0 + 4 * kc);
            *(short4v*)&As[row][4 * kc] = av;
        }
#pragma unroll
        for (int i = 0; i < 4; i++) {
            int idx = t + 256 * i;
            int kr = idx >> 5, nc = idx & 31;
            short4v bv = *(const short4v*)(B + (size_t)(k0 + kr) * 4096 + n0 + 4 * nc);
#pragma unroll
            for (int j = 0; j < 4; j++) Bs[4 * nc + j][kr] = (unsigned short)bv[j];
        }
        __syncthreads();

        short8v af[4];
#pragma unroll
        for (int mi = 0; mi < 4; mi++) {
            int ar = wrow * 64 + mi * 16 + l15;
            short4v a0 = *(const short4v*)&As[ar][4 * lg];
            short4v a1 = *(const short4v*)&As[ar][16 + 4 * lg];
            af[mi] = __builtin_shufflevector(a0, a1, 0, 1, 2, 3, 4, 5, 6, 7);
        }
#pragma unroll
        for (int ni = 0; ni < 4; ni++) {
            int bc = wcol * 64 + ni * 16 + l15;
            short4v b0 = *(const short4v*)&Bs[bc][4 * lg];
            short4v b1 = *(const short4v*)&Bs[bc][16 + 4 * lg];
            short8v bf = __builtin_shufflevector(b0, b1, 0, 1, 2, 3, 4, 5, 6, 7);
#pragma unroll
            for (int mi = 0; mi < 4; mi++) acc[mi][ni] = MFMA16(af[mi], bf, acc[mi][ni]);
        }
        __syncthreads();
    }
#pragma unroll
    for (int mi = 0; mi < 4; mi++)
#pragma unroll
        for (int ni = 0; ni < 4; ni++) {
            int row = m0 + wrow * 64 + mi * 16 + 4 * lg;
            int col = n0 + wcol * 64 + ni * 16 + l15;
#pragma unroll
            for (int r = 0; r < 4; r++)
                C[(size_t)(row + r) * 4096 + col] = bf16r(acc[mi][ni][r]);
        }
}

// ---------------- bf16 GEMM: C[512,4096] = A[512,512] * BT[4096,512]^T ----------------
// BT is n-major (attn_bT): Bs staging is a straight vector copy, no transpose.
__global__ __launch_bounds__(256) void k_gemmT(const unsigned short* __restrict__ A,
                                               const unsigned short* __restrict__ BT,
                                               unsigned short* __restrict__ C) {
    __shared__ unsigned short As[128][36];
    __shared__ unsigned short Bs[128][36];
    int t = threadIdx.x;
    int w = t >> 6, l = t & 63, l15 = l & 15, lg = l >> 4;
    int wrow = w >> 1, wcol = w & 1;
    int m0 = blockIdx.y * 128, n0 = blockIdx.x * 128;
    f32x4 acc[4][4] = {};

    for (int k0 = 0; k0 < 512; k0 += 32) {
#pragma unroll
        for (int i = 0; i < 4; i++) {
            int idx = t + 256 * i;
            int row = idx >> 3, kc = idx & 7;
            short4v av = *(const short4v*)(A + (size_t)(m0 + row) * 512 + k0 + 4 * kc);
            *(short4v*)&As[row][4 * kc] = av;
            short4v bv = *(const short4v*)(BT + (size_t)(n0 + row) * 512 + k0 + 4 * kc);
            *(short4v*)&Bs[row][4 * kc] = bv;
        }
        __syncthreads();

        short8v af[4];
#pragma unroll
        for (int mi = 0; mi < 4; mi++) {
            int ar = wrow * 64 + mi * 16 + l15;
            short4v a0 = *(const short4v*)&As[ar][4 * lg];
            short4v a1 = *(const short4v*)&As[ar][16 + 4 * lg];
            af[mi] = __builtin_shufflevector(a0, a1, 0, 1, 2, 3, 4, 5, 6, 7);
        }
#pragma unroll
        for (int ni = 0; ni < 4; ni++) {
            int bc = wcol * 64 + ni * 16 + l15;
            short4v b0 = *(const short4v*)&Bs[bc][4 * lg];
            short4v b1 = *(const short4v*)&Bs[bc][16 + 4 * lg];
            short8v bf = __builtin_shufflevector(b0, b1, 0, 1, 2, 3, 4, 5, 6, 7);
#pragma unroll
            for (int mi = 0; mi < 4; mi++) acc[mi][ni] = MFMA16(af[mi], bf, acc[mi][ni]);
        }
        __syncthreads();
    }
#pragma unroll
    for (int mi = 0; mi < 4; mi++)
#pragma unroll
        for (int ni = 0; ni < 4; ni++) {
            int row = m0 + wrow * 64 + mi * 16 + 4 * lg;
            int col = n0 + wcol * 64 + ni * 16 + l15;
#pragma unroll
            for (int r = 0; r < 4; r++)
                C[(size_t)(row + r) * 4096 + col] = bf16r(acc[mi][ni][r]);
        }
}

// ---------------- fragment-order permute prepass ----------------
__global__ __launch_bounds__(256) void k_perm(const unsigned short* __restrict__ qkv,
                                              unsigned short* __restrict__ qtg,
                                              unsigned short* __restrict__ ktg,
                                              unsigned short* __restrict__ vtg) {
    __shared__ unsigned short lt[64][72];
    int t = threadIdx.x;
    int tile = blockIdx.x, h = blockIdx.y, z = blockIdx.z;
    int base = (z == 0 ? 0 : (z == 1 ? 512 : 1024)) + h * 64;
#pragma unroll
    for (int i = 0; i < 2; i++) {
        int idx = t + 256 * i;
        int row = idx >> 3, sg = idx & 7;
        *(short8v*)&lt[row][sg * 8] =
            *(const short8v*)(qkv + (size_t)(base + row) * 4096 + tile * 64 + sg * 8);
    }
    __syncthreads();
#pragma unroll
    for (int i = 0; i < 2; i++) {
        int c = t + 256 * i;
        unsigned short o[8];
        unsigned short* dst;
        if (z == 0) {
            int nh = c >> 8, cl = c & 255;
            int s = cl >> 7, lgc = (cl >> 5) & 3, col = cl & 31;
#pragma unroll
            for (int j = 0; j < 4; j++) {
                o[j] = lt[s * 32 + 4 * lgc + j][nh * 32 + col];
                o[4 + j] = lt[s * 32 + 16 + 4 * lgc + j][nh * 32 + col];
            }
            dst = qtg + ((size_t)(h * 128 + tile * 2 + nh)) * 2048 + cl * 8;
        } else if (z == 1) {
            int s = c >> 8, lgc = (c >> 6) & 3, m = c & 63;
#pragma unroll
            for (int j = 0; j < 4; j++) {
                o[j] = lt[s * 32 + 4 * lgc + j][m];
                o[4 + j] = lt[s * 32 + 16 + 4 * lgc + j][m];
            }
            dst = ktg + ((size_t)(h * 64 + tile)) * 4096 + c * 8;
        } else {
            int mh = c >> 8, lgc = (c >> 6) & 3, d = c & 63;
#pragma unroll
            for (int j = 0; j < 4; j++) {
                o[j] = lt[d][mh * 32 + 4 * lgc + j];
                o[4 + j] = lt[d][mh * 32 + 16 + 4 * lgc + j];
            }
            dst = vtg + ((size_t)(h * 64 + tile)) * 4096 + c * 8;
        }
        *(short8v*)dst = *(const short8v*)o;
    }
}

// ---------------- flash attention: 4-wave blocks @ 5/CU, dbuf, counted vmcnt ----------------
// grid (32 qt, 8 h, 8 seg), 256 threads. Wave w -> 32 n (nu = qt*4+w); segment = 512 keys
// = 8 tiles of 64. m==0 softmax (log2e folded in Wq), lane-local l. LDS 32KB (2x8KB K,V).
// Per tile j: STAGE(j+1) -> vmcnt(4) [stage(j) done, stage(j+1) in flight] -> barrier ->
// compute(j) -> barrier (consume-guard).
__global__ __launch_bounds__(256, 5) void k_attn(const unsigned short* __restrict__ qtg,
                                                 const unsigned short* __restrict__ ktg,
                                                 const unsigned short* __restrict__ vtg,
                                                 unsigned short* __restrict__ opart,
                                                 float* __restrict__ lgl) {
    __shared__ __align__(16) unsigned short kbuf[2][4096];
    __shared__ __align__(16) unsigned short vbuf[2][4096];
    int t = threadIdx.x;
    int l = t & 63, l15 = l & 15, lg = l >> 4, w = t >> 6;
    int qt = blockIdx.x, h = blockIdx.y, seg = blockIdx.z;
    int nu = qt * 4 + w;

    const unsigned short* qb = qtg + ((size_t)(h * 128 + nu)) * 2048;
    const unsigned short* kb = ktg + ((size_t)(h * 64 + seg * 8)) * 4096;
    const unsigned short* vb = vtg + ((size_t)(h * 64 + seg * 8)) * 4096;

    short8v qf[2][2];
#pragma unroll
    for (int ng = 0; ng < 2; ng++)
#pragma unroll
        for (int s = 0; s < 2; s++)
            qf[ng][s] = *(const short8v*)(qb + ((s * 4 + lg) * 32 + ng * 16 + l15) * 8);

    f32x4 od[2][4] = {};
    float lsum[2] = {0.f, 0.f};

#define STAGE(kt, b)                                                            \
    {                                                                           \
        gload16(kb + (size_t)(kt) * 4096 + t * 8, &kbuf[b][t * 8]);             \
        gload16(kb + (size_t)(kt) * 4096 + (t + 256) * 8, &kbuf[b][(t + 256) * 8]); \
        gload16(vb + (size_t)(kt) * 4096 + t * 8, &vbuf[b][t * 8]);             \
        gload16(vb + (size_t)(kt) * 4096 + (t + 256) * 8, &vbuf[b][(t + 256) * 8]); \
    }

    STAGE(0, 0);

    int u = 0;
#pragma unroll 1
    for (int j = 0; j < 8; j++) {
        if (j < 7) {
            STAGE(j + 1, u ^ 1);
            asm volatile("s_waitcnt vmcnt(4)" ::: "memory");  // stage(j) done, j+1 in flight
        } else {
            asm volatile("s_waitcnt vmcnt(0)" ::: "memory");
        }
        __builtin_amdgcn_s_barrier();
        __builtin_amdgcn_sched_barrier(0);

        const unsigned short* kl = &kbuf[u][0];
        const unsigned short* vl = &vbuf[u][0];

        // phase 1: S^T for 64 keys (4 mf frags), exp2 inline, pack P progressively
        u32x4 pwA, pwB;
        short8v pb[2][2];
#pragma unroll
        for (int mf = 0; mf < 4; mf++) {
            short8v k0 = *(const short8v*)(kl + ((0 + lg) * 64 + mf * 16 + l15) * 8);
            short8v k1 = *(const short8v*)(kl + ((4 + lg) * 64 + mf * 16 + l15) * 8);
            f32x4 s0 = {}, s1 = {};
            __builtin_amdgcn_s_setprio(1);
            s0 = MFMA16(k0, qf[0][0], s0);
            s0 = MFMA16(k1, qf[0][1], s0);
            s1 = MFMA16(k0, qf[1][0], s1);
            s1 = MFMA16(k1, qf[1][1], s1);
            __builtin_amdgcn_s_setprio(0);
            float p0[4], p1[4];
#pragma unroll
            for (int r = 0; r < 4; r++) {
                p0[r] = __builtin_amdgcn_exp2f(s0[r]);
                p1[r] = __builtin_amdgcn_exp2f(s1[r]);
            }
            lsum[0] += (p0[0] + p0[1]) + (p0[2] + p0[3]);
            lsum[1] += (p1[0] + p1[1]) + (p1[2] + p1[3]);
            if (!(mf & 1)) {
                pwA[0] = __builtin_amdgcn_perm(fbits(p0[1]), fbits(p0[0]), 0x07060302u);
                pwA[1] = __builtin_amdgcn_perm(fbits(p0[3]), fbits(p0[2]), 0x07060302u);
                pwB[0] = __builtin_amdgcn_perm(fbits(p1[1]), fbits(p1[0]), 0x07060302u);
                pwB[1] = __builtin_amdgcn_perm(fbits(p1[3]), fbits(p1[2]), 0x07060302u);
            } else {
                pwA[2] = __builtin_amdgcn_perm(fbits(p0[1]), fbits(p0[0]), 0x07060302u);
                pwA[3] = __builtin_amdgcn_perm(fbits(p0[3]), fbits(p0[2]), 0x07060302u);
                pwB[2] = __builtin_amdgcn_perm(fbits(p1[1]), fbits(p1[0]), 0x07060302u);
                pwB[3] = __builtin_amdgcn_perm(fbits(p1[3]), fbits(p1[2]), 0x07060302u);
                pb[0][mf >> 1] = __builtin_bit_cast(short8v, pwA);
                pb[1][mf >> 1] = __builtin_bit_cast(short8v, pwB);
            }
        }

        // phase 2: O^T += V P^T (two 32-key halves)
        __builtin_amdgcn_s_setprio(1);
#pragma unroll
        for (int mh = 0; mh < 2; mh++)
#pragma unroll
            for (int dg = 0; dg < 4; dg++) {
                short8v vf = *(const short8v*)(vl + ((mh * 4 + lg) * 64 + dg * 16 + l15) * 8);
                od[0][dg] = MFMA16(vf, pb[0][mh], od[0][dg]);
                od[1][dg] = MFMA16(vf, pb[1][mh], od[1][dg]);
            }
        __builtin_amdgcn_s_setprio(0);

        __builtin_amdgcn_s_barrier();  // consume-guard
        u ^= 1;
    }
#undef STAGE

#pragma unroll
    for (int ng = 0; ng < 2; ng++) {
        lsum[ng] += __shfl_xor(lsum[ng], 16, 64);
        lsum[ng] += __shfl_xor(lsum[ng], 32, 64);
    }

    // coalesced partial store: opart[seg][h][n][d], short4 (d-contiguous)
    unsigned short* op = opart + (((size_t)(seg * 8 + h)) * 4096 + nu * 32) * 64;
#pragma unroll
    for (int ng = 0; ng < 2; ng++)
#pragma unroll
        for (int dg = 0; dg < 4; dg++) {
            unsigned short v4[4];
#pragma unroll
            for (int r = 0; r < 4; r++) v4[r] = bf16r(od[ng][dg][r]);
            *(short4v*)(op + (ng * 16 + l15) * 64 + dg * 16 + 4 * lg) = *(const short4v*)v4;
        }
    if (lg == 0) {
#pragma unroll
        for (int ng = 0; ng < 2; ng++)
            lgl[(size_t)(seg * 8 + h) * 4096 + nu * 32 + ng * 16 + l15] = lsum[ng];
    }
}

// ---------------- merge 8 seg partials -> attn_bT (n-major), fully coalesced ----------------
__global__ __launch_bounds__(256) void k_merge(const unsigned short* __restrict__ opart,
                                               const float* __restrict__ lgl,
                                               unsigned short* __restrict__ attn_bT) {
    int t = threadIdx.x;
    int n = blockIdx.x * 8 + (t >> 5);
    int cid = t & 31;
    int h = cid >> 2, d0 = (cid & 3) * 16;

    float den = 0.f;
    float num[16] = {};
#pragma unroll
    for (int s = 0; s < 8; s++) {
        den += lgl[(size_t)(s * 8 + h) * 4096 + n];
        const unsigned short* row = opart + (((size_t)(s * 8 + h)) * 4096 + n) * 64 + d0;
        short8v a = *(const short8v*)row;
        short8v b = *(const short8v*)(row + 8);
#pragma unroll
        for (int j = 0; j < 8; j++) {
            num[j] += bff((unsigned short)a[j]);
            num[8 + j] += bff((unsigned short)b[j]);
        }
    }
    float inv = 1.0f / den;
    unsigned short res[16];
#pragma unroll
    for (int j = 0; j < 16; j++) res[j] = bf16r(num[j] * inv);
    unsigned short* dst = attn_bT + (size_t)n * 512 + h * 64 + d0;
    *(short8v*)dst = *(const short8v*)&res[0];
    *(short8v*)(dst + 8) = *(const short8v*)&res[8];
}

// ---------------- bilinear upsample 64->256 + bias + residual (float4) ----------------
__global__ __launch_bounds__(256) void k_up(const float* __restrict__ x,
                                            const unsigned short* __restrict__ low,
                                            const float* __restrict__ proj_b,
                                            const float* __restrict__ gamma,
                                            float* __restrict__ out) {
    int t = threadIdx.x;
    int hs = t >> 6;
    int hh = blockIdx.x * 4 + hs;
    int c = blockIdx.y;
    int a = t & 63;

    int ph = hh & 3, Ah = hh >> 2;
    int y0 = Ah + ((ph < 2) ? -1 : 0);
    float fy = (ph < 2) ? (0.625f + 0.25f * ph) : (0.125f + 0.25f * (ph - 2));
    int y1 = min(y0 + 1, 63); y0 = max(y0, 0);

    const unsigned short* L0 = low + (size_t)c * 4096 + y0 * 64;
    const unsigned short* L1 = low + (size_t)c * 4096 + y1 * 64;
    int am = max(a - 1, 0), ap = min(a + 1, 63);
    float gy = 1.f - fy;
    float vm = gy * bff(L0[am]) + fy * bff(L1[am]);
    float v0 = gy * bff(L0[a])  + fy * bff(L1[a]);
    float vp = gy * bff(L0[ap]) + fy * bff(L1[ap]);

    float pb = proj_b[c], g = gamma[0];
    size_t idx = (size_t)c * 65536 + (size_t)hh * 256 + a * 4;
    float4 xi = *(const float4*)(x + idx);
    float4 o;
    o.x = xi.x + g * (0.375f * vm + 0.625f * v0 + pb);
    o.y = xi.y + g * (0.125f * vm + 0.875f * v0 + pb);
    o.z = xi.z + g * (0.875f * v0 + 0.125f * vp + pb);
    o.w = xi.w + g * (0.625f * v0 + 0.375f * vp + pb);
    *(float4*)(out + idx) = o;
}

extern "C" void kernel_launch(void* const* d_in, const int* in_sizes, int n_in,
                              void* d_out, int out_size, void* d_ws, size_t ws_size,
                              hipStream_t stream) {
    const float* x     = (const float*)d_in[0];
    const float* gnw   = (const float*)d_in[1];
    const float* gnb   = (const float*)d_in[2];
    const float* qkvw  = (const float*)d_in[3];
    const float* projw = (const float*)d_in[4];
    const float* projb = (const float*)d_in[5];
    const float* gamma = (const float*)d_in[6];
    const float* temp  = (const float*)d_in[7];

    char* ws = (char*)d_ws;
    const size_t MB = 1u << 20;
    float* gstats          = (float*)(ws + 0);
    float* partials        = (float*)(ws + 1024);
    float* xp              = (float*)(ws + 1 * MB);            // dead after k_xr
    unsigned short* qtg    = (unsigned short*)(ws + 1 * MB);   // reuses xp (4MB)
    unsigned short* ktg    = (unsigned short*)(ws + 5 * MB);   // 4MB
    unsigned short* xr_b   = (unsigned short*)(ws + 9 * MB);   // dead after gemm1
    unsigned short* vtg    = (unsigned short*)(ws + 9 * MB);   // reuses xr_b (4MB)
    unsigned short* wq_b   = (unsigned short*)(ws + 13 * MB);
    unsigned short* wp_b   = (unsigned short*)(ws + 15 * MB);
    unsigned short* qkv_b  = (unsigned short*)(ws + 16 * MB);
    unsigned short* attn_bT= (unsigned short*)(ws + 28 * MB);  // n-major (4096,512)
    unsigned short* low_b  = (unsigned short*)(ws + 32 * MB);
    float* out = (float*)d_out;
    unsigned short* opart = (unsigned short*)d_out;              // 33.5MB scratch in d_out
    float* lgl = (float*)((char*)d_out + 40 * MB);               // 1MB scratch in d_out

    k_pool<<<dim3(72, 512), 256, 0, stream>>>(x, xp, partials, qkvw, projw, temp, wq_b, wp_b);
    k_stats<<<8, 256, 0, stream>>>(partials, gstats);
    k_xr<<<8192, 256, 0, stream>>>(xp, gstats, gnw, gnb, xr_b);
    k_gemm<<<dim3(32, 12), 256, 0, stream>>>(wq_b, xr_b, qkv_b);
    k_perm<<<dim3(64, 8, 3), 256, 0, stream>>>(qkv_b, qtg, ktg, vtg);
    k_attn<<<dim3(32, 8, 8), 256, 0, stream>>>(qtg, ktg, vtg, opart, lgl);
    k_merge<<<512, 256, 0, stream>>>(opart, lgl, attn_bT);
    k_gemmT<<<dim3(32, 4), 256, 0, stream>>>(wp_b, attn_bT, low_b);
    k_up<<<dim3(64, 512), 256, 0, stream>>>(x, low_b, projb, gamma, out);
}

// Round 10
// 179.681 us; speedup vs baseline: 1.0574x; 1.0328x over previous
//
#include <hip/hip_runtime.h>
#include <hip/hip_bf16.h>

// Pipeline (8 launches):
//  k_pool   : x -> pooled xp + group partial stats  [+ fused wconv: weights -> bf16]
//  k_stats  : reduce partials -> mean/rstd per group
//  k_xr     : xr = GN_affine(xp) + posenc -> bf16 (512,4096)
//  k_gemmP  : qkv = Wq(1536,512) x xr -> fragment-ordered qtg/ktg/vtg DIRECTLY
//             (perm fused into epilogue; no qkv_b round-trip)
//  k_attn   : flash attn, m==0 softmax, lane-local l, 64-key tiles, dbuf LDS,
//             counted vmcnt, 4 segments (grid 1024 = 4 blocks/CU)
//  k_merge  : sum 4 seg partials -> attn_bT (n-major) bf16
//  k_gemmT  : low = Wp(512,512) x attn_bT^T, 64-row tiles (grid 256 = all CUs)
//  k_up     : out = x + gamma * (bilerp_4x(low) + proj_b), nontemporal stores

typedef __attribute__((ext_vector_type(4))) short short4v;
typedef __attribute__((ext_vector_type(8))) short short8v;
typedef __attribute__((ext_vector_type(4))) float f32x4;
typedef __attribute__((ext_vector_type(4))) unsigned int u32x4;

#define MFMA16(a, b, c) __builtin_amdgcn_mfma_f32_16x16x32_bf16(a, b, c, 0, 0, 0)

__device__ __forceinline__ unsigned short bf16r(float f) {
    unsigned int u = __builtin_bit_cast(unsigned int, f);
    u += 0x7fffu + ((u >> 16) & 1u);
    return (unsigned short)(u >> 16);
}
__device__ __forceinline__ float bff(unsigned short s) {
    unsigned int u = ((unsigned int)s) << 16;
    return __builtin_bit_cast(float, u);
}
__device__ __forceinline__ unsigned int fbits(float f) {
    return __builtin_bit_cast(unsigned int, f);
}

typedef const __attribute__((address_space(1))) unsigned int guint;
typedef __attribute__((address_space(3))) unsigned int luint;
__device__ __forceinline__ void gload16(const void* g, void* l) {
    __builtin_amdgcn_global_load_lds((guint*)g, (luint*)l, 16, 0, 0);
}

// ---------------- pool + group partial stats (+ fused weight conversion) ----------------
__global__ __launch_bounds__(256) void k_pool(const float* __restrict__ x,
                                              float* __restrict__ xp,
                                              float* __restrict__ partials,
                                              const float* __restrict__ qkv_w,
                                              const float* __restrict__ proj_w,
                                              const float* __restrict__ temp,
                                              unsigned short* __restrict__ wq_b,
                                              unsigned short* __restrict__ wp_b) {
    if (blockIdx.x >= 64) {
        int idx = ((blockIdx.x - 64) * 512 + blockIdx.y) * 256 + threadIdx.x;
        const int NQ = 1536 * 512;
        const int NTOT = NQ + 512 * 512;
        if (idx < NQ) {
            int o = idx >> 9;
            float sc = (o < 512) ? temp[o >> 6] * 0.125f * 1.44269504f : 1.0f;
            wq_b[idx] = bf16r(qkv_w[idx] * sc);
        } else if (idx < NTOT) {
            wp_b[idx - NQ] = bf16r(proj_w[idx - NQ]);
        }
        return;
    }
    int hr = blockIdx.x;
    int c  = blockIdx.y;
    int t = threadIdx.x;
    int r = t >> 6, wq = t & 63;
    const float4* src = (const float4*)(x + (size_t)c * 65536 + (size_t)(4 * hr + r) * 256 + 4 * wq);
    float4 v = *src;
    float s4 = v.x + v.y + v.z + v.w;
    float q4 = v.x * v.x + v.y * v.y + v.z * v.z + v.w * v.w;

    __shared__ float sm[256];
    __shared__ float wq4[4];
    sm[t] = s4;
    float qq = q4;
#pragma unroll
    for (int off = 1; off < 64; off <<= 1) qq += __shfl_xor(qq, off, 64);
    if ((t & 63) == 0) wq4[t >> 6] = qq;
    __syncthreads();
    if (t < 64) {
        float cs = sm[t] + sm[64 + t] + sm[128 + t] + sm[192 + t];
        xp[(size_t)c * 4096 + hr * 64 + t] = cs * (1.0f / 16.0f);
        float ts = cs;
#pragma unroll
        for (int off = 1; off < 64; off <<= 1) ts += __shfl_xor(ts, off, 64);
        if (t == 0) {
            int g = c >> 6;
            int slot = (c & 63) * 64 + hr;
            partials[(size_t)(g * 4096 + slot) * 2 + 0] = ts;
            partials[(size_t)(g * 4096 + slot) * 2 + 1] = wq4[0] + wq4[1] + wq4[2] + wq4[3];
        }
    }
}

// ---------------- group stats finalize ----------------
__global__ __launch_bounds__(256) void k_stats(const float* __restrict__ partials,
                                               float* __restrict__ gstats) {
    int g = blockIdx.x;
    int t = threadIdx.x;
    float s = 0.f, q = 0.f;
    for (int i = t; i < 4096; i += 256) {
        s += partials[(size_t)(g * 4096 + i) * 2 + 0];
        q += partials[(size_t)(g * 4096 + i) * 2 + 1];
    }
#pragma unroll
    for (int off = 1; off < 64; off <<= 1) {
        s += __shfl_xor(s, off, 64);
        q += __shfl_xor(q, off, 64);
    }
    __shared__ float ss[4], qs[4];
    if ((t & 63) == 0) { ss[t >> 6] = s; qs[t >> 6] = q; }
    __syncthreads();
    if (t == 0) {
        float S = ss[0] + ss[1] + ss[2] + ss[3];
        float Q = qs[0] + qs[1] + qs[2] + qs[3];
        const float inv = 1.0f / 4194304.0f;
        float m = S * inv;
        float var = Q * inv - m * m;
        gstats[2 * g] = m;
        gstats[2 * g + 1] = rsqrtf(var + 1e-5f);
    }
}

// ---------------- GN affine + positional encoding -> bf16 ----------------
__global__ __launch_bounds__(256) void k_xr(const float* __restrict__ xp,
                                            const float* __restrict__ gs,
                                            const float* __restrict__ gw,
                                            const float* __restrict__ gb,
                                            unsigned short* __restrict__ xr) {
    int idx = blockIdx.x * 256 + threadIdx.x;
    int c = idx >> 12, n = idx & 4095;
    int hr = n >> 6, wr = n & 63;
    int g = c >> 6;
    float m = gs[2 * g], rs = gs[2 * g + 1];
    float xn = (xp[idx] - m) * rs * gw[c] + gb[c];
    int i = c >> 2, kind = c & 3;
    float di = expf(-(float)i * 0.07195578415606394f);
    float arg = ((kind < 2) ? (float)hr : (float)wr) * di;
    float pe = 0.01f * ((kind & 1) ? cosf(arg) : sinf(arg));
    xr[idx] = bf16r(xn + pe);
}

// ---------------- QKV GEMM with fused fragment-order epilogue ----------------
// C[1536,4096] = Wq[1536,512] x xr[512,4096]; output written DIRECTLY in the
// fragment-ordered layouts consumed by k_attn (mapping identical to old k_perm).
// blockIdx.y: 0-3 -> Q section, 4-7 -> K, 8-11 -> V. Block tile 128 rows x 128 cols.
__global__ __launch_bounds__(256) void k_gemmP(const unsigned short* __restrict__ A,
                                               const unsigned short* __restrict__ B,
                                               unsigned short* __restrict__ qtg,
                                               unsigned short* __restrict__ ktg,
                                               unsigned short* __restrict__ vtg) {
    __shared__ __align__(16) char smem[33792];
    unsigned short (*As)[36] = (unsigned short(*)[36])smem;
    unsigned short (*Bs)[36] = (unsigned short(*)[36])(smem + 9216);
    unsigned short (*ct)[132] = (unsigned short(*)[132])smem;  // epilogue reuse

    int t = threadIdx.x;
    int w = t >> 6, l = t & 63, l15 = l & 15, lg = l >> 4;
    int wrow = w >> 1, wcol = w & 1;
    int m0 = blockIdx.y * 128, n0 = blockIdx.x * 128;
    f32x4 acc[4][4] = {};

    for (int k0 = 0; k0 < 512; k0 += 32) {
#pragma unroll
        for (int i = 0; i < 4; i++) {
            int idx = t + 256 * i;
            int row = idx >> 3, kc = idx & 7;
            short4v av = *(const short4v*)(A + (size_t)(m0 + row) * 512 + k0 + 4 * kc);
            *(short4v*)&As[row][4 * kc] = av;
        }
#pragma unroll
        for (int i = 0; i < 4; i++) {
            int idx = t + 256 * i;
            int kr = idx >> 5, nc = idx & 31;
            short4v bv = *(const short4v*)(B + (size_t)(k0 + kr) * 4096 + n0 + 4 * nc);
#pragma unroll
            for (int j = 0; j < 4; j++) Bs[4 * nc + j][kr] = (unsigned short)bv[j];
        }
        __syncthreads();

        short8v af[4];
#pragma unroll
        for (int mi = 0; mi < 4; mi++) {
            int ar = wrow * 64 + mi * 16 + l15;
            short4v a0 = *(const short4v*)&As[ar][4 * lg];
            short4v a1 = *(const short4v*)&As[ar][16 + 4 * lg];
            af[mi] = __builtin_shufflevector(a0, a1, 0, 1, 2, 3, 4, 5, 6, 7);
        }
#pragma unroll
        for (int ni = 0; ni < 4; ni++) {
            int bc = wcol * 64 + ni * 16 + l15;
            short4v b0 = *(const short4v*)&Bs[bc][4 * lg];
            short4v b1 = *(const short4v*)&Bs[bc][16 + 4 * lg];
            short8v bf = __builtin_shufflevector(b0, b1, 0, 1, 2, 3, 4, 5, 6, 7);
#pragma unroll
            for (int mi = 0; mi < 4; mi++) acc[mi][ni] = MFMA16(af[mi], bf, acc[mi][ni]);
        }
        __syncthreads();
    }

    // epilogue: acc -> LDS tile ct[mloc][nloc] (bf16)
#pragma unroll
    for (int mi = 0; mi < 4; mi++)
#pragma unroll
        for (int ni = 0; ni < 4; ni++) {
            int ml = wrow * 64 + mi * 16 + 4 * lg;
            int nl = wcol * 64 + ni * 16 + l15;
#pragma unroll
            for (int r = 0; r < 4; r++) ct[ml + r][nl] = bf16r(acc[mi][ni][r]);
        }
    __syncthreads();

    int y = blockIdx.y;
#pragma unroll
    for (int i = 0; i < 8; i++) {
        int gc = t + 256 * i;  // [0, 2048)
        int hg = gc >> 10, rem = gc & 1023;
        unsigned short o[8];
        unsigned short* dst;
        if (y < 4) {  // Q: per (h, nu) 256 chunks; chunk c=(s*4+lg)*32+col32
            int nu_loc = rem >> 8, cidx = rem & 255;
            int s = cidx >> 7, lgc = (cidx >> 5) & 3, col = cidx & 31;
#pragma unroll
            for (int j = 0; j < 4; j++) {
                o[j] = ct[hg * 64 + s * 32 + 4 * lgc + j][nu_loc * 32 + col];
                o[4 + j] = ct[hg * 64 + s * 32 + 16 + 4 * lgc + j][nu_loc * 32 + col];
            }
            int h = y * 2 + hg;
            dst = qtg + ((size_t)(h * 128 + (n0 >> 5) + nu_loc)) * 2048 + cidx * 8;
        } else if (y < 8) {  // K: per (h, T) 512 chunks; chunk c=(s*4+lg)*64+m64
            int Tloc = rem >> 9, cidx = rem & 511;
            int s = cidx >> 8, lgc = (cidx >> 6) & 3, m64 = cidx & 63;
#pragma unroll
            for (int j = 0; j < 4; j++) {
                o[j] = ct[hg * 64 + s * 32 + 4 * lgc + j][Tloc * 64 + m64];
                o[4 + j] = ct[hg * 64 + s * 32 + 16 + 4 * lgc + j][Tloc * 64 + m64];
            }
            int h = (y - 4) * 2 + hg;
            dst = ktg + ((size_t)(h * 64 + (n0 >> 6) + Tloc)) * 4096 + cidx * 8;
        } else {  // V: per (h, T) 512 chunks; chunk c=(mh*4+lg)*64+d
            int Tloc = rem >> 9, cidx = rem & 511;
            int mh = cidx >> 8, lgc = (cidx >> 6) & 3, d = cidx & 63;
#pragma unroll
            for (int j = 0; j < 4; j++) {
                o[j] = ct[hg * 64 + d][Tloc * 64 + mh * 32 + 4 * lgc + j];
                o[4 + j] = ct[hg * 64 + d][Tloc * 64 + mh * 32 + 16 + 4 * lgc + j];
            }
            int h = (y - 8) * 2 + hg;
            dst = vtg + ((size_t)(h * 64 + (n0 >> 6) + Tloc)) * 4096 + cidx * 8;
        }
        *(short8v*)dst = *(const short8v*)o;
    }
}

// ---------------- flash attention: 4 segs, dbuf, counted vmcnt ----------------
// grid (32 qt, 8 h, 4 seg), 256 threads. Wave w -> 32 n; segment = 1024 keys = 16 tiles.
__global__ __launch_bounds__(256, 5) void k_attn(const unsigned short* __restrict__ qtg,
                                                 const unsigned short* __restrict__ ktg,
                                                 const unsigned short* __restrict__ vtg,
                                                 unsigned short* __restrict__ opart,
                                                 float* __restrict__ lgl) {
    __shared__ __align__(16) unsigned short kbuf[2][4096];
    __shared__ __align__(16) unsigned short vbuf[2][4096];
    int t = threadIdx.x;
    int l = t & 63, l15 = l & 15, lg = l >> 4, w = t >> 6;
    int qt = blockIdx.x, h = blockIdx.y, seg = blockIdx.z;
    int nu = qt * 4 + w;

    const unsigned short* qb = qtg + ((size_t)(h * 128 + nu)) * 2048;
    const unsigned short* kb = ktg + ((size_t)(h * 64 + seg * 16)) * 4096;
    const unsigned short* vb = vtg + ((size_t)(h * 64 + seg * 16)) * 4096;

    short8v qf[2][2];
#pragma unroll
    for (int ng = 0; ng < 2; ng++)
#pragma unroll
        for (int s = 0; s < 2; s++)
            qf[ng][s] = *(const short8v*)(qb + ((s * 4 + lg) * 32 + ng * 16 + l15) * 8);

    f32x4 od[2][4] = {};
    float lsum[2] = {0.f, 0.f};

#define STAGE(kt, b)                                                            \
    {                                                                           \
        gload16(kb + (size_t)(kt) * 4096 + t * 8, &kbuf[b][t * 8]);             \
        gload16(kb + (size_t)(kt) * 4096 + (t + 256) * 8, &kbuf[b][(t + 256) * 8]); \
        gload16(vb + (size_t)(kt) * 4096 + t * 8, &vbuf[b][t * 8]);             \
        gload16(vb + (size_t)(kt) * 4096 + (t + 256) * 8, &vbuf[b][(t + 256) * 8]); \
    }

    STAGE(0, 0);

    int u = 0;
#pragma unroll 1
    for (int j = 0; j < 16; j++) {
        if (j < 15) {
            STAGE(j + 1, u ^ 1);
            asm volatile("s_waitcnt vmcnt(4)" ::: "memory");
        } else {
            asm volatile("s_waitcnt vmcnt(0)" ::: "memory");
        }
        __builtin_amdgcn_s_barrier();
        __builtin_amdgcn_sched_barrier(0);

        const unsigned short* kl = &kbuf[u][0];
        const unsigned short* vl = &vbuf[u][0];

        u32x4 pwA, pwB;
        short8v pb[2][2];
#pragma unroll
        for (int mf = 0; mf < 4; mf++) {
            short8v k0 = *(const short8v*)(kl + ((0 + lg) * 64 + mf * 16 + l15) * 8);
            short8v k1 = *(const short8v*)(kl + ((4 + lg) * 64 + mf * 16 + l15) * 8);
            f32x4 s0 = {}, s1 = {};
            __builtin_amdgcn_s_setprio(1);
            s0 = MFMA16(k0, qf[0][0], s0);
            s0 = MFMA16(k1, qf[0][1], s0);
            s1 = MFMA16(k0, qf[1][0], s1);
            s1 = MFMA16(k1, qf[1][1], s1);
            __builtin_amdgcn_s_setprio(0);
            float p0[4], p1[4];
#pragma unroll
            for (int r = 0; r < 4; r++) {
                p0[r] = __builtin_amdgcn_exp2f(s0[r]);
                p1[r] = __builtin_amdgcn_exp2f(s1[r]);
            }
            lsum[0] += (p0[0] + p0[1]) + (p0[2] + p0[3]);
            lsum[1] += (p1[0] + p1[1]) + (p1[2] + p1[3]);
            if (!(mf & 1)) {
                pwA[0] = __builtin_amdgcn_perm(fbits(p0[1]), fbits(p0[0]), 0x07060302u);
                pwA[1] = __builtin_amdgcn_perm(fbits(p0[3]), fbits(p0[2]), 0x07060302u);
                pwB[0] = __builtin_amdgcn_perm(fbits(p1[1]), fbits(p1[0]), 0x07060302u);
                pwB[1] = __builtin_amdgcn_perm(fbits(p1[3]), fbits(p1[2]), 0x07060302u);
            } else {
                pwA[2] = __builtin_amdgcn_perm(fbits(p0[1]), fbits(p0[0]), 0x07060302u);
                pwA[3] = __builtin_amdgcn_perm(fbits(p0[3]), fbits(p0[2]), 0x07060302u);
                pwB[2] = __builtin_amdgcn_perm(fbits(p1[1]), fbits(p1[0]), 0x07060302u);
                pwB[3] = __builtin_amdgcn_perm(fbits(p1[3]), fbits(p1[2]), 0x07060302u);
                pb[0][mf >> 1] = __builtin_bit_cast(short8v, pwA);
                pb[1][mf >> 1] = __builtin_bit_cast(short8v, pwB);
            }
        }

        __builtin_amdgcn_s_setprio(1);
#pragma unroll
        for (int mh = 0; mh < 2; mh++)
#pragma unroll
            for (int dg = 0; dg < 4; dg++) {
                short8v vf = *(const short8v*)(vl + ((mh * 4 + lg) * 64 + dg * 16 + l15) * 8);
                od[0][dg] = MFMA16(vf, pb[0][mh], od[0][dg]);
                od[1][dg] = MFMA16(vf, pb[1][mh], od[1][dg]);
            }
        __builtin_amdgcn_s_setprio(0);

        __builtin_amdgcn_s_barrier();
        u ^= 1;
    }
#undef STAGE

#pragma unroll
    for (int ng = 0; ng < 2; ng++) {
        lsum[ng] += __shfl_xor(lsum[ng], 16, 64);
        lsum[ng] += __shfl_xor(lsum[ng], 32, 64);
    }

    unsigned short* op = opart + (((size_t)(seg * 8 + h)) * 4096 + nu * 32) * 64;
#pragma unroll
    for (int ng = 0; ng < 2; ng++)
#pragma unroll
        for (int dg = 0; dg < 4; dg++) {
            unsigned short v4[4];
#pragma unroll
            for (int r = 0; r < 4; r++) v4[r] = bf16r(od[ng][dg][r]);
            *(short4v*)(op + (ng * 16 + l15) * 64 + dg * 16 + 4 * lg) = *(const short4v*)v4;
        }
    if (lg == 0) {
#pragma unroll
        for (int ng = 0; ng < 2; ng++)
            lgl[(size_t)(seg * 8 + h) * 4096 + nu * 32 + ng * 16 + l15] = lsum[ng];
    }
}

// ---------------- merge 4 seg partials -> attn_bT (n-major), coalesced ----------------
__global__ __launch_bounds__(256) void k_merge(const unsigned short* __restrict__ opart,
                                               const float* __restrict__ lgl,
                                               unsigned short* __restrict__ attn_bT) {
    int t = threadIdx.x;
    int n = blockIdx.x * 8 + (t >> 5);
    int cid = t & 31;
    int h = cid >> 2, d0 = (cid & 3) * 16;

    float den = 0.f;
    float num[16] = {};
#pragma unroll
    for (int s = 0; s < 4; s++) {
        den += lgl[(size_t)(s * 8 + h) * 4096 + n];
        const unsigned short* row = opart + (((size_t)(s * 8 + h)) * 4096 + n) * 64 + d0;
        short8v a = *(const short8v*)row;
        short8v b = *(const short8v*)(row + 8);
#pragma unroll
        for (int j = 0; j < 8; j++) {
            num[j] += bff((unsigned short)a[j]);
            num[8 + j] += bff((unsigned short)b[j]);
        }
    }
    float inv = 1.0f / den;
    unsigned short res[16];
#pragma unroll
    for (int j = 0; j < 16; j++) res[j] = bf16r(num[j] * inv);
    unsigned short* dst = attn_bT + (size_t)n * 512 + h * 64 + d0;
    *(short8v*)dst = *(const short8v*)&res[0];
    *(short8v*)(dst + 8) = *(const short8v*)&res[8];
}

// ---------------- proj GEMM: C[512,4096] = A[512,512] x BT[4096,512]^T ----------------
// 64-row tiles -> grid (32,8) = 256 blocks (every CU busy). BT n-major: straight copy staging.
__global__ __launch_bounds__(256) void k_gemmT(const unsigned short* __restrict__ A,
                                               const unsigned short* __restrict__ BT,
                                               unsigned short* __restrict__ C) {
    __shared__ unsigned short As[64][36];
    __shared__ unsigned short Bs[128][36];
    int t = threadIdx.x;
    int w = t >> 6, l = t & 63, l15 = l & 15, lg = l >> 4;
    int wrow = w >> 1, wcol = w & 1;
    int m0 = blockIdx.y * 64, n0 = blockIdx.x * 128;
    f32x4 acc[2][4] = {};

    for (int k0 = 0; k0 < 512; k0 += 32) {
#pragma unroll
        for (int i = 0; i < 2; i++) {
            int idx = t + 256 * i;
            int row = idx >> 3, kc = idx & 7;
            short4v av = *(const short4v*)(A + (size_t)(m0 + row) * 512 + k0 + 4 * kc);
            *(short4v*)&As[row][4 * kc] = av;
        }
#pragma unroll
        for (int i = 0; i < 4; i++) {
            int idx = t + 256 * i;
            int row = idx >> 3, kc = idx & 7;
            short4v bv = *(const short4v*)(BT + (size_t)(n0 + row) * 512 + k0 + 4 * kc);
            *(short4v*)&Bs[row][4 * kc] = bv;
        }
        __syncthreads();

        short8v af[2];
#pragma unroll
        for (int mi = 0; mi < 2; mi++) {
            int ar = wrow * 32 + mi * 16 + l15;
            short4v a0 = *(const short4v*)&As[ar][4 * lg];
            short4v a1 = *(const short4v*)&As[ar][16 + 4 * lg];
            af[mi] = __builtin_shufflevector(a0, a1, 0, 1, 2, 3, 4, 5, 6, 7);
        }
#pragma unroll
        for (int ni = 0; ni < 4; ni++) {
            int bc = wcol * 64 + ni * 16 + l15;
            short4v b0 = *(const short4v*)&Bs[bc][4 * lg];
            short4v b1 = *(const short4v*)&Bs[bc][16 + 4 * lg];
            short8v bf = __builtin_shufflevector(b0, b1, 0, 1, 2, 3, 4, 5, 6, 7);
#pragma unroll
            for (int mi = 0; mi < 2; mi++) acc[mi][ni] = MFMA16(af[mi], bf, acc[mi][ni]);
        }
        __syncthreads();
    }
#pragma unroll
    for (int mi = 0; mi < 2; mi++)
#pragma unroll
        for (int ni = 0; ni < 4; ni++) {
            int row = m0 + wrow * 32 + mi * 16 + 4 * lg;
            int col = n0 + wcol * 64 + ni * 16 + l15;
#pragma unroll
            for (int r = 0; r < 4; r++)
                C[(size_t)(row + r) * 4096 + col] = bf16r(acc[mi][ni][r]);
        }
}

// ---------------- bilinear upsample 64->256 + bias + residual (float4, NT store) ----------------
__global__ __launch_bounds__(256) void k_up(const float* __restrict__ x,
                                            const unsigned short* __restrict__ low,
                                            const float* __restrict__ proj_b,
                                            const float* __restrict__ gamma,
                                            float* __restrict__ out) {
    int t = threadIdx.x;
    int hs = t >> 6;
    int hh = blockIdx.x * 4 + hs;
    int c = blockIdx.y;
    int a = t & 63;

    int ph = hh & 3, Ah = hh >> 2;
    int y0 = Ah + ((ph < 2) ? -1 : 0);
    float fy = (ph < 2) ? (0.625f + 0.25f * ph) : (0.125f + 0.25f * (ph - 2));
    int y1 = min(y0 + 1, 63); y0 = max(y0, 0);

    const unsigned short* L0 = low + (size_t)c * 4096 + y0 * 64;
    const unsigned short* L1 = low + (size_t)c * 4096 + y1 * 64;
    int am = max(a - 1, 0), ap = min(a + 1, 63);
    float gy = 1.f - fy;
    float vm = gy * bff(L0[am]) + fy * bff(L1[am]);
    float v0 = gy * bff(L0[a])  + fy * bff(L1[a]);
    float vp = gy * bff(L0[ap]) + fy * bff(L1[ap]);

    float pb = proj_b[c], g = gamma[0];
    size_t idx = (size_t)c * 65536 + (size_t)hh * 256 + a * 4;
    float4 xi = *(const float4*)(x + idx);
    f32x4 o;
    o[0] = xi.x + g * (0.375f * vm + 0.625f * v0 + pb);
    o[1] = xi.y + g * (0.125f * vm + 0.875f * v0 + pb);
    o[2] = xi.z + g * (0.875f * v0 + 0.125f * vp + pb);
    o[3] = xi.w + g * (0.625f * v0 + 0.375f * vp + pb);
    __builtin_nontemporal_store(o, (f32x4*)(out + idx));
}

extern "C" void kernel_launch(void* const* d_in, const int* in_sizes, int n_in,
                              void* d_out, int out_size, void* d_ws, size_t ws_size,
                              hipStream_t stream) {
    const float* x     = (const float*)d_in[0];
    const float* gnw   = (const float*)d_in[1];
    const float* gnb   = (const float*)d_in[2];
    const float* qkvw  = (const float*)d_in[3];
    const float* projw = (const float*)d_in[4];
    const float* projb = (const float*)d_in[5];
    const float* gamma = (const float*)d_in[6];
    const float* temp  = (const float*)d_in[7];

    char* ws = (char*)d_ws;
    const size_t MB = 1u << 20;
    float* gstats          = (float*)(ws + 0);
    float* partials        = (float*)(ws + 1024);
    float* xp              = (float*)(ws + 1 * MB);            // dead after k_xr
    unsigned short* qtg    = (unsigned short*)(ws + 1 * MB);   // reuses xp (4MB)
    unsigned short* ktg    = (unsigned short*)(ws + 5 * MB);   // 4MB
    unsigned short* xr_b   = (unsigned short*)(ws + 9 * MB);   // dead after gemmP... kept until gemmP done
    unsigned short* vtg    = (unsigned short*)(ws + 13 * MB);  // 4MB (xr_b still live during gemmP)
    unsigned short* wq_b   = (unsigned short*)(ws + 17 * MB);
    unsigned short* wp_b   = (unsigned short*)(ws + 19 * MB);
    unsigned short* attn_bT= (unsigned short*)(ws + 21 * MB);  // n-major (4096,512)
    unsigned short* low_b  = (unsigned short*)(ws + 25 * MB);
    float* out = (float*)d_out;
    unsigned short* opart = (unsigned short*)d_out;              // 16MB scratch in d_out
    float* lgl = (float*)((char*)d_out + 16 * MB);               // 0.5MB scratch in d_out

    k_pool<<<dim3(72, 512), 256, 0, stream>>>(x, xp, partials, qkvw, projw, temp, wq_b, wp_b);
    k_stats<<<8, 256, 0, stream>>>(partials, gstats);
    k_xr<<<8192, 256, 0, stream>>>(xp, gstats, gnw, gnb, xr_b);
    k_gemmP<<<dim3(32, 12), 256, 0, stream>>>(wq_b, xr_b, qtg, ktg, vtg);
    k_attn<<<dim3(32, 8, 4), 256, 0, stream>>>(qtg, ktg, vtg, opart, lgl);
    k_merge<<<512, 256, 0, stream>>>(opart, lgl, attn_bT);
    k_gemmT<<<dim3(32, 8), 256, 0, stream>>>(wp_b, attn_bT, low_b);
    k_up<<<dim3(64, 512), 256, 0, stream>>>(x, low_b, projb, gamma, out);
}